// Round 6
// baseline (123.104 us; speedup 1.0000x reference)
//
#include <hip/hip_runtime.h>
#include <hip/hip_bf16.h>
#include <math.h>

typedef __attribute__((ext_vector_type(8))) __bf16 bf16x8;
typedef __attribute__((ext_vector_type(4))) float f32x4;

// ws layout (bf16 element offsets). Weights packed in MFMA B-fragment order:
// pack[ks][n][lane][j] = W[k = ks*32 + (lane>>4)*8 + j][col = n*16 + (lane&15)]
#define OFF_W1P    0         // W1 pack [16][8][64][8]
#define OFF_W2P    65536     // W2 pack [4][8][64][8]
#define OFF_W3P    81920     // W3 pack [4][8][64][8]
#define OFF_WINP   98304     // Win pack [4][32][64][8]
#define OFF_WOUTP  163840    // Wout pack [16][8][64][8]
#define NPACK      229376

// Compact tanh-form gelu (abs err ~1e-4 << 0.074 margin)
__device__ __forceinline__ float gelu_f(float x) {
  float t = 1.5957691216f * x * (1.0f + 0.044715f * x * x);
  return __fdividef(x, 1.0f + __expf(-t));
}

__device__ __forceinline__ bf16x8 cvt8(float4 u, float4 v) {
  bf16x8 r;
  r[0] = (__bf16)u.x; r[1] = (__bf16)u.y; r[2] = (__bf16)u.z; r[3] = (__bf16)u.w;
  r[4] = (__bf16)v.x; r[5] = (__bf16)v.y; r[6] = (__bf16)v.z; r[7] = (__bf16)v.w;
  return r;
}

// Barrier that drains LDS ops only — outstanding global loads (which target
// per-thread VGPRs, no cross-wave state) stay in flight across it.
__device__ __forceinline__ void bar_lgkm() {
  asm volatile("s_waitcnt lgkmcnt(0)\n\ts_barrier" ::: "memory");
}

#define MFMA __builtin_amdgcn_mfma_f32_16x16x32_bf16

// ---------------- prep: weight fragment-packing only (bf16) ----------------
__global__ __launch_bounds__(256) void prep_kernel(
    const float* __restrict__ W1, const float* __restrict__ W2,
    const float* __restrict__ W3, const float* __restrict__ Wi,
    const float* __restrict__ Wo, __bf16* __restrict__ wsb)
{
  int i = blockIdx.x * 256 + threadIdx.x;
  float v;
  if (i < 65536) {                    // W1 pack, src W1[512][128]
    int j = i;
    int jj = j & 7, ln = (j >> 3) & 63, n = (j >> 9) & 7, ks = j >> 12;
    int k = ks * 32 + (ln >> 4) * 8 + jj, h = n * 16 + (ln & 15);
    v = W1[k * 128 + h];
  } else if (i < 81920) {             // W2 pack, src W2[128][128]
    int j = i - 65536;
    int jj = j & 7, ln = (j >> 3) & 63, n = (j >> 9) & 7, ks = j >> 12;
    int k = ks * 32 + (ln >> 4) * 8 + jj, g = n * 16 + (ln & 15);
    v = W2[k * 128 + g];
  } else if (i < 98304) {             // W3 pack, src W3[128][128]
    int j = i - 81920;
    int jj = j & 7, ln = (j >> 3) & 63, n = (j >> 9) & 7, ks = j >> 12;
    int k = ks * 32 + (ln >> 4) * 8 + jj, h = n * 16 + (ln & 15);
    v = W3[k * 128 + h];
  } else if (i < 163840) {            // Win pack, src Win[128][512]
    int j = i - 98304;
    int jj = j & 7, ln = (j >> 3) & 63, n = (j >> 9) & 31, ks = j >> 14;
    int k = ks * 32 + (ln >> 4) * 8 + jj, o = n * 16 + (ln & 15);
    v = Wi[k * 512 + o];
  } else {                            // Wout pack, src Wout[512][128]
    int j = i - 163840;
    int jj = j & 7, ln = (j >> 3) & 63, n = (j >> 9) & 7, ks = j >> 12;
    int k = ks * 32 + (ln >> 4) * 8 + jj, h = n * 16 + (ln & 15);
    v = Wo[k * 128 + h];
  }
  wsb[i] = (__bf16)v;
}

// ------- fully fused: edge MLP + masked K-reduce + LN1 + FFN + LN2 + mask ----
// block = 2 nodes (96 edge rows), 4 waves. Wave w owns output cols
// [w*32, w*32+32) of BOTH nodes -> acc[2][3][2] = 48 VGPRs.
// hE staged via dbuf LDS [96][64]bf16 (12KB x2), XOR-swizzled, ONE raw
// lgkm-barrier per chunk (global prefetch stays in flight), depth-3 prefetch.
// Tail: per-block FFN for the 2 nodes (M padded to 16), writes `out` direct.
__global__ __launch_bounds__(256, 3) void edge_mlp_kernel(
    const float* __restrict__ hE, const float* __restrict__ hV,
    const float* __restrict__ mask_att, const __bf16* __restrict__ wsb,
    const float* __restrict__ b1, const float* __restrict__ b2,
    const float* __restrict__ b3,
    const float* __restrict__ Winb, const float* __restrict__ Woutb,
    const float* __restrict__ ns1, const float* __restrict__ no1,
    const float* __restrict__ ns2, const float* __restrict__ no2,
    const float* __restrict__ maskV, float* __restrict__ out)
{
  __shared__ char lds[24576];   // A dbuf (2x12288) == X region == tail buffers

  const int tid = threadIdx.x;
  const int w = tid >> 6, lane = tid & 63;
  const int lo = lane & 15, hi = lane >> 4;
  const int n0 = blockIdx.x * 2;

  const __bf16* W1p = wsb + OFF_W1P;

  f32x4 acc[2][3][2];
#pragma unroll
  for (int nl = 0; nl < 2; nl++)
#pragma unroll
    for (int m = 0; m < 3; m++)
#pragma unroll
      for (int nn = 0; nn < 2; nn++) {
        acc[nl][m][nn][0] = 0.f; acc[nl][m][nn][1] = 0.f;
        acc[nl][m][nn][2] = 0.f; acc[nl][m][nn][3] = 0.f;
      }

  // Per-thread staging tasks: 3 tasks, each = 32B of one hE row-chunk.
  const float* tsrc[3];
  int tdst[3];
#pragma unroll
  for (int p = 0; p < 3; p++) {
    int s = p * 256 + tid;          // 0..767
    int row = s >> 3, c8 = s & 7;   // row 0..95, 8 x 32B segments
    int nl = (row >= 48) ? 1 : 0, kk = row - nl * 48;
    tsrc[p] = hE + ((size_t)((n0 + nl) * 48 + kk)) * 384 + c8 * 8;
    tdst[p] = row * 128 + ((c8 * 16) ^ ((row & 7) << 4));
  }

  // ---- prologue: issue e0->f, e1->g; compute h_V k-steps; write e0; issue e2->f
  float4 f1[3], f2[3], g1[3], g2[3];
#pragma unroll
  for (int p = 0; p < 3; p++) { f1[p] = *(const float4*)(tsrc[p]);      f2[p] = *(const float4*)(tsrc[p] + 4); }
#pragma unroll
  for (int p = 0; p < 3; p++) { g1[p] = *(const float4*)(tsrc[p] + 64); g2[p] = *(const float4*)(tsrc[p] + 68); }

#pragma unroll 1
  for (int ks = 0; ks < 4; ++ks) {
    const float* v0 = hV + (n0)     * 128 + ks * 32 + hi * 8;
    const float* v1 = hV + (n0 + 1) * 128 + ks * 32 + hi * 8;
    bf16x8 a0 = cvt8(*(const float4*)v0, *(const float4*)(v0 + 4));
    bf16x8 a1 = cvt8(*(const float4*)v1, *(const float4*)(v1 + 4));
#pragma unroll
    for (int nn = 0; nn < 2; nn++) {
      bf16x8 b = *(const bf16x8*)(W1p + ((ks * 8 + w * 2 + nn) << 9) + lane * 8);
#pragma unroll
      for (int m = 0; m < 3; m++) {
        acc[0][m][nn] = MFMA(a0, b, acc[0][m][nn], 0, 0, 0);
        acc[1][m][nn] = MFMA(a1, b, acc[1][m][nn], 0, 0, 0);
      }
    }
  }
#pragma unroll
  for (int p = 0; p < 3; p++)
    *(bf16x8*)(lds + tdst[p]) = cvt8(f1[p], f2[p]);        // e0 -> buf0
#pragma unroll
  for (int p = 0; p < 3; p++) { f1[p] = *(const float4*)(tsrc[p] + 128); f2[p] = *(const float4*)(tsrc[p] + 132); }  // e2
  bar_lgkm();

  // ---- main loop: hE chunks e=0..5 (k-steps 4..15), 1 barrier per chunk ----
#pragma unroll 1
  for (int i = 0; i < 6; ++i) {
    // publish chunk e_{i+1} into the other buffer (regs loaded 2 iters ago)
    if (i < 5) {
      if ((i & 1) == 0) {
#pragma unroll
        for (int p = 0; p < 3; p++) *(bf16x8*)(lds + 12288 - (i & 1) * 12288 + tdst[p]) = cvt8(g1[p], g2[p]);
      } else {
#pragma unroll
        for (int p = 0; p < 3; p++) *(bf16x8*)(lds + 12288 - (i & 1) * 12288 + tdst[p]) = cvt8(f1[p], f2[p]);
      }
    }
    // issue loads for chunk e_{i+3}
    if (i <= 2) {
      const int of = (i + 3) * 64;
      if ((i & 1) == 0) {
#pragma unroll
        for (int p = 0; p < 3; p++) { g1[p] = *(const float4*)(tsrc[p] + of); g2[p] = *(const float4*)(tsrc[p] + of + 4); }
      } else {
#pragma unroll
        for (int p = 0; p < 3; p++) { f1[p] = *(const float4*)(tsrc[p] + of); f2[p] = *(const float4*)(tsrc[p] + of + 4); }
      }
    }
    // compute chunk e_i from buf[i&1]
    {
      const char* Ab = lds + (i & 1) * 12288;
#pragma unroll
      for (int ks32 = 0; ks32 < 2; ++ks32) {
        int ks = 4 + i * 2 + ks32;
        bf16x8 bb[2];
#pragma unroll
        for (int nn = 0; nn < 2; nn++)
          bb[nn] = *(const bf16x8*)(W1p + ((ks * 8 + w * 2 + nn) << 9) + lane * 8);
        bf16x8 a[2][3];
#pragma unroll
        for (int nl = 0; nl < 2; nl++)
#pragma unroll
          for (int m = 0; m < 3; m++) {
            int row = nl * 48 + m * 16 + lo;
            a[nl][m] = *(const bf16x8*)(Ab + row * 128 + ((ks32 * 64 + hi * 16) ^ ((row & 7) << 4)));
          }
#pragma unroll
        for (int nn = 0; nn < 2; nn++)
#pragma unroll
          for (int nl = 0; nl < 2; nl++)
#pragma unroll
            for (int m = 0; m < 3; m++)
              acc[nl][m][nn] = MFMA(a[nl][m], bb[nn], acc[nl][m][nn], 0, 0, 0);
      }
    }
    if (i < 5) bar_lgkm();
  }

  // ---- layers 2 and 3: A[96,128] @ W[128,128], X lives in the A region ----
#pragma unroll 1
  for (int layer = 0; layer < 2; ++layer) {
    const float*  bv = layer ? b2 : b1;
    const __bf16* Wp = wsb + (layer ? OFF_W3P : OFF_W2P);
    __syncthreads();   // everyone done reading lds (GEMM1 or previous layer)
#pragma unroll
    for (int nn = 0; nn < 2; nn++) {
      int col = (w * 2 + nn) * 16 + lo;
      float bc = bv[col];
#pragma unroll
      for (int nl = 0; nl < 2; nl++)
#pragma unroll
        for (int m = 0; m < 3; m++)
#pragma unroll
          for (int i = 0; i < 4; i++) {
            int row = nl * 48 + m * 16 + hi * 4 + i;
            float g = gelu_f(acc[nl][m][nn][i] + bc);
            *(__bf16*)(lds + row * 256 + ((col * 2) ^ ((row & 7) << 4))) = (__bf16)g;
            acc[nl][m][nn][i] = 0.f;
          }
    }
    __syncthreads();   // X visible to all waves
#pragma unroll 1
    for (int kc2 = 0; kc2 < 2; ++kc2) {
#pragma unroll
      for (int ks32 = 0; ks32 < 2; ++ks32) {
        int ks = kc2 * 2 + ks32;
        bf16x8 bb[2];
#pragma unroll
        for (int nn = 0; nn < 2; nn++)
          bb[nn] = *(const bf16x8*)(Wp + ((ks * 8 + w * 2 + nn) << 9) + lane * 8);
        bf16x8 a[2][3];
#pragma unroll
        for (int nl = 0; nl < 2; nl++)
#pragma unroll
          for (int m = 0; m < 3; m++) {
            int row = nl * 48 + m * 16 + lo;
            a[nl][m] = *(const bf16x8*)(lds + row * 256 + ((kc2 * 128 + ks32 * 64 + hi * 16) ^ ((row & 7) << 4)));
          }
#pragma unroll
        for (int nn = 0; nn < 2; nn++)
#pragma unroll
          for (int nl = 0; nl < 2; nl++)
#pragma unroll
            for (int m = 0; m < 3; m++)
              acc[nl][m][nn] = MFMA(a[nl][m], bb[nn], acc[nl][m][nn], 0, 0, 0);
      }
    }
  }

  // ================== fused tail: K-reduce + LN1 + FFN + LN2 ==================
  // LDS tail layout (X is dead after the barrier below):
  char*  xA    = lds;                       // [16][256B] bf16, swizzled (rows 0,1 = nodes)
  float* hvnl  = (float*)(lds + 4096);      // [2][128] f32
  float* dhl   = (float*)(lds + 5120);      // [2][128] f32
  float* part  = (float*)(lds + 6144);      // [8] f32 reduce partials
  float* redl  = (float*)(lds + 6400);      // [2][128] f32
  char*  A2    = lds + 8192;                // [16][1024B] bf16, swizzled

  __syncthreads();   // (A) all layer-3 LDS reads done; X dead

  // epilogue: + b3, * mask_attend, sum over 48 rows per node, /SCALE -> dhl
#pragma unroll
  for (int nl = 0; nl < 2; nl++) {
    float msk[12];
#pragma unroll
    for (int m = 0; m < 3; m++)
#pragma unroll
      for (int i = 0; i < 4; i++)
        msk[m * 4 + i] = mask_att[(n0 + nl) * 48 + m * 16 + hi * 4 + i];
#pragma unroll
    for (int nn = 0; nn < 2; nn++) {
      int col = (w * 2 + nn) * 16 + lo;
      float bc = b3[col];
      float s = 0.f;
#pragma unroll
      for (int m = 0; m < 3; m++)
#pragma unroll
        for (int i = 0; i < 4; i++)
          s += (acc[nl][m][nn][i] + bc) * msk[m * 4 + i];
      s += __shfl_xor(s, 16);
      s += __shfl_xor(s, 32);
      if (hi == 0)
        dhl[nl * 128 + col] = s * (1.0f / 30.0f);
    }
  }
  // zero xA rows 2..15 (pad rows for the M=16 MFMA)
  if (tid < 224) { bf16x8 z = {}; *(bf16x8*)(xA + 512 + tid * 16) = z; }
  __syncthreads();   // (B) dhl + zero-pad visible

  // LN1: r = node (0..1), c = feature (0..127); 2 waves per node
  {
    const int r = tid >> 7, c = tid & 127;
    float x = hV[(n0 + r) * 128 + c] + dhl[r * 128 + c];
    float s = x, sq = x * x;
#pragma unroll
    for (int off = 32; off >= 1; off >>= 1) { s += __shfl_xor(s, off); sq += __shfl_xor(sq, off); }
    if (lane == 0) { part[w * 2] = s; part[w * 2 + 1] = sq; }
    __syncthreads();   // (C)
    float st = part[4 * r] + part[4 * r + 2];
    float sqt = part[4 * r + 1] + part[4 * r + 3];
    float mean = st * (1.f / 128.f);
    float var  = sqt * (1.f / 128.f) - mean * mean;
    float rs = rsqrtf(var + 1e-5f);
    float y = (x - mean) * rs * ns1[c] + no1[c];
    hvnl[r * 128 + c] = y;
    *(__bf16*)(xA + r * 256 + (((c >> 3) * 16) ^ (r << 4)) + (c & 7) * 2) = (__bf16)y;
  }
  __syncthreads();   // (D) xA ready

  // FFN1: [16,128] @ Win -> [16,512]; wave w owns cols w*128..+127
  {
    const __bf16* Winp = wsb + OFF_WINP;
    f32x4 acc1[8];
#pragma unroll
    for (int n = 0; n < 8; n++) { acc1[n][0] = 0.f; acc1[n][1] = 0.f; acc1[n][2] = 0.f; acc1[n][3] = 0.f; }
#pragma unroll
    for (int ks = 0; ks < 4; ks++) {
      const int kb = (ks * 32 + hi * 8) * 2;
      bf16x8 a = *(const bf16x8*)(xA + lo * 256 + (kb ^ ((lo & 7) << 4)));
#pragma unroll
      for (int n = 0; n < 8; n++) {
        int ng = w * 8 + n;
        bf16x8 b = *(const bf16x8*)(Winp + ((ks * 32 + ng) << 9) + lane * 8);
        acc1[n] = MFMA(a, b, acc1[n], 0, 0, 0);
      }
    }
    // gelu -> A2 [16][1024B] swizzled
#pragma unroll
    for (int n = 0; n < 8; n++) {
      int col = w * 128 + n * 16 + lo;
      float bc = Winb[col];
#pragma unroll
      for (int i = 0; i < 4; i++) {
        int r2 = hi * 4 + i;
        float g = gelu_f(acc1[n][i] + bc);
        *(__bf16*)(A2 + r2 * 1024 + ((col * 2) ^ ((r2 & 7) << 4))) = (__bf16)g;
      }
    }
  }
  __syncthreads();   // (E) A2 ready

  // FFN2: [16,512] @ Wout -> [16,128]; wave w owns cols w*32..+31
  {
    const __bf16* Woutp = wsb + OFF_WOUTP;
    f32x4 acc2[2];
    acc2[0][0] = 0.f; acc2[0][1] = 0.f; acc2[0][2] = 0.f; acc2[0][3] = 0.f;
    acc2[1][0] = 0.f; acc2[1][1] = 0.f; acc2[1][2] = 0.f; acc2[1][3] = 0.f;
#pragma unroll
    for (int ks = 0; ks < 16; ks++) {
      const int kb = (ks * 32 + hi * 8) * 2;
      bf16x8 a = *(const bf16x8*)(A2 + lo * 1024 + (kb ^ ((lo & 7) << 4)));
#pragma unroll
      for (int n = 0; n < 2; n++) {
        int ng = w * 2 + n;
        bf16x8 b = *(const bf16x8*)(Woutp + ((ks * 8 + ng) << 9) + lane * 8);
        acc2[n] = MFMA(a, b, acc2[n], 0, 0, 0);
      }
    }
    // rows 0,1 (hi==0, i<2) -> redl
#pragma unroll
    for (int n = 0; n < 2; n++) {
      int col = w * 32 + n * 16 + lo;
      float bc = Woutb[col];
#pragma unroll
      for (int i = 0; i < 2; i++)
        if (hi == 0)
          redl[i * 128 + col] = acc2[n][i] + bc;
    }
  }
  __syncthreads();   // (F) redl ready

  // LN2(hvnl + redl) * mask_V -> out
  {
    const int r = tid >> 7, c = tid & 127;
    float x = hvnl[r * 128 + c] + redl[r * 128 + c];
    float s = x, sq = x * x;
#pragma unroll
    for (int off = 32; off >= 1; off >>= 1) { s += __shfl_xor(s, off); sq += __shfl_xor(sq, off); }
    if (lane == 0) { part[w * 2] = s; part[w * 2 + 1] = sq; }
    __syncthreads();   // (G)
    float st = part[4 * r] + part[4 * r + 2];
    float sqt = part[4 * r + 1] + part[4 * r + 3];
    float mean = st * (1.f / 128.f);
    float var  = sqt * (1.f / 128.f) - mean * mean;
    float rs = rsqrtf(var + 1e-5f);
    out[(n0 + r) * 128 + c] = maskV[n0 + r] * ((x - mean) * rs * ns2[c] + no2[c]);
  }
}

extern "C" void kernel_launch(void* const* d_in, const int* in_sizes, int n_in,
                              void* d_out, int out_size, void* d_ws, size_t ws_size,
                              hipStream_t stream)
{
  (void)in_sizes; (void)n_in; (void)out_size; (void)ws_size;
  const float* hV   = (const float*)d_in[0];
  const float* hE   = (const float*)d_in[1];
  const float* mV   = (const float*)d_in[2];
  const float* mAtt = (const float*)d_in[3];
  const float* W1   = (const float*)d_in[4];
  const float* b1   = (const float*)d_in[5];
  const float* W2   = (const float*)d_in[6];
  const float* b2   = (const float*)d_in[7];
  const float* W3   = (const float*)d_in[8];
  const float* b3   = (const float*)d_in[9];
  const float* Win  = (const float*)d_in[10];
  const float* binb = (const float*)d_in[11];
  const float* Wout = (const float*)d_in[12];
  const float* bout = (const float*)d_in[13];
  const float* ns1  = (const float*)d_in[14];
  const float* no1  = (const float*)d_in[15];
  const float* ns2  = (const float*)d_in[16];
  const float* no2  = (const float*)d_in[17];

  __bf16* wsb = (__bf16*)d_ws;
  float* out  = (float*)d_out;

  prep_kernel<<<NPACK / 256, 256, 0, stream>>>(W1, W2, W3, Win, Wout, wsb);
  edge_mlp_kernel<<<2048, 256, 0, stream>>>(hE, hV, mAtt, wsb, b1, b2, b3,
                                            binb, bout, ns1, no1, ns2, no2,
                                            mV, out);
}

// Round 7
// 110.693 us; speedup vs baseline: 1.1121x; 1.1121x over previous
//
#include <hip/hip_runtime.h>
#include <hip/hip_bf16.h>
#include <math.h>

typedef __attribute__((ext_vector_type(8))) __bf16 bf16x8;
typedef __attribute__((ext_vector_type(4))) float f32x4;

// ws layout (bf16 element offsets). Weights packed in MFMA B-fragment order:
// pack[ks][n][lane][j] = W[k = ks*32 + (lane>>4)*8 + j][col = n*16 + (lane&15)]
#define OFF_W1P    0         // W1 pack [16][8][64][8]
#define OFF_W2P    65536     // W2 pack [4][8][64][8]
#define OFF_W3P    81920     // W3 pack [4][8][64][8]
#define OFF_WINP   98304     // Win pack [4][32][64][8]
#define OFF_WOUTP  163840    // Wout pack [16][8][64][8]
#define NPACK      229376
#define OFF_DH_BYTES 458752  // f32 dh [4096][128] right after the bf16 packs

// Compact tanh-form gelu (abs err ~1e-4 << 0.074 margin)
__device__ __forceinline__ float gelu_f(float x) {
  float t = 1.5957691216f * x * (1.0f + 0.044715f * x * x);
  return __fdividef(x, 1.0f + __expf(-t));
}

__device__ __forceinline__ bf16x8 cvt8(float4 u, float4 v) {
  bf16x8 r;
  r[0] = (__bf16)u.x; r[1] = (__bf16)u.y; r[2] = (__bf16)u.z; r[3] = (__bf16)u.w;
  r[4] = (__bf16)v.x; r[5] = (__bf16)v.y; r[6] = (__bf16)v.z; r[7] = (__bf16)v.w;
  return r;
}

// Barrier that drains LDS ops only — outstanding global loads (which target
// per-thread VGPRs, no cross-wave state) stay in flight across it.
__device__ __forceinline__ void bar_lgkm() {
  asm volatile("s_waitcnt lgkmcnt(0)\n\ts_barrier" ::: "memory");
}

#define MFMA __builtin_amdgcn_mfma_f32_16x16x32_bf16

// ---------------- prep: weight fragment-packing only (bf16) ----------------
__global__ __launch_bounds__(256) void prep_kernel(
    const float* __restrict__ W1, const float* __restrict__ W2,
    const float* __restrict__ W3, const float* __restrict__ Wi,
    const float* __restrict__ Wo, __bf16* __restrict__ wsb)
{
  int i = blockIdx.x * 256 + threadIdx.x;
  float v;
  if (i < 65536) {                    // W1 pack, src W1[512][128]
    int j = i;
    int jj = j & 7, ln = (j >> 3) & 63, n = (j >> 9) & 7, ks = j >> 12;
    int k = ks * 32 + (ln >> 4) * 8 + jj, h = n * 16 + (ln & 15);
    v = W1[k * 128 + h];
  } else if (i < 81920) {             // W2 pack, src W2[128][128]
    int j = i - 65536;
    int jj = j & 7, ln = (j >> 3) & 63, n = (j >> 9) & 7, ks = j >> 12;
    int k = ks * 32 + (ln >> 4) * 8 + jj, g = n * 16 + (ln & 15);
    v = W2[k * 128 + g];
  } else if (i < 98304) {             // W3 pack, src W3[128][128]
    int j = i - 81920;
    int jj = j & 7, ln = (j >> 3) & 63, n = (j >> 9) & 7, ks = j >> 12;
    int k = ks * 32 + (ln >> 4) * 8 + jj, h = n * 16 + (ln & 15);
    v = W3[k * 128 + h];
  } else if (i < 163840) {            // Win pack, src Win[128][512]
    int j = i - 98304;
    int jj = j & 7, ln = (j >> 3) & 63, n = (j >> 9) & 31, ks = j >> 14;
    int k = ks * 32 + (ln >> 4) * 8 + jj, o = n * 16 + (ln & 15);
    v = Wi[k * 512 + o];
  } else {                            // Wout pack, src Wout[512][128]
    int j = i - 163840;
    int jj = j & 7, ln = (j >> 3) & 63, n = (j >> 9) & 7, ks = j >> 12;
    int k = ks * 32 + (ln >> 4) * 8 + jj, h = n * 16 + (ln & 15);
    v = Wo[k * 128 + h];
  }
  wsb[i] = (__bf16)v;
}

// ---------------- kernel 1: fused edge MLP + masked K-reduce ----------------
// block = 2 nodes (96 edge rows), 4 waves. Wave w owns output cols
// [w*32, w*32+32) of BOTH nodes -> acc[2][3][2] = 48 VGPRs.
// hE staged via dbuf LDS [96][64]bf16 (12KB x2), XOR-swizzled. Per chunk:
// publish(ds_write) -> WEIGHT LOADS FIRST -> hE prefetch issue -> ds_read+MFMA
// -> lgkm-only barrier. Weight use then waits vmcnt(6): the 6 hE loads stay
// in flight, so the HBM stream never drains (vmcnt is in-order).
__global__ __launch_bounds__(256, 3) void edge_mlp_kernel(
    const float* __restrict__ hE, const float* __restrict__ hV,
    const float* __restrict__ mask_att, const __bf16* __restrict__ wsb,
    const float* __restrict__ b1, const float* __restrict__ b2,
    const float* __restrict__ b3, float* __restrict__ dh)
{
  __shared__ char lds[24576];   // A dbuf (2x12288) == X region (96 rows x 256B)

  const int tid = threadIdx.x;
  const int w = tid >> 6, lane = tid & 63;
  const int lo = lane & 15, hi = lane >> 4;
  const int n0 = blockIdx.x * 2;

  const __bf16* W1p = wsb + OFF_W1P;

  f32x4 acc[2][3][2];
#pragma unroll
  for (int nl = 0; nl < 2; nl++)
#pragma unroll
    for (int m = 0; m < 3; m++)
#pragma unroll
      for (int nn = 0; nn < 2; nn++) {
        acc[nl][m][nn][0] = 0.f; acc[nl][m][nn][1] = 0.f;
        acc[nl][m][nn][2] = 0.f; acc[nl][m][nn][3] = 0.f;
      }

  // Per-thread staging tasks: 3 tasks, each = 32B of one hE row-chunk.
  const float* tsrc[3];
  int tdst[3];
#pragma unroll
  for (int p = 0; p < 3; p++) {
    int s = p * 256 + tid;          // 0..767
    int row = s >> 3, c8 = s & 7;   // row 0..95, 8 x 32B segments
    int nl = (row >= 48) ? 1 : 0, kk = row - nl * 48;
    tsrc[p] = hE + ((size_t)((n0 + nl) * 48 + kk)) * 384 + c8 * 8;
    tdst[p] = row * 128 + ((c8 * 16) ^ ((row & 7) << 4));
  }

  // ---- prologue: issue e0->A, e1->B; compute h_V part; publish e0; issue e2->A
  float4 pA1[3], pA2[3], pB1[3], pB2[3];
#pragma unroll
  for (int p = 0; p < 3; p++) { pA1[p] = *(const float4*)(tsrc[p]);      pA2[p] = *(const float4*)(tsrc[p] + 4); }
#pragma unroll
  for (int p = 0; p < 3; p++) { pB1[p] = *(const float4*)(tsrc[p] + 64); pB2[p] = *(const float4*)(tsrc[p] + 68); }

#pragma unroll 1
  for (int ks = 0; ks < 4; ++ks) {
    const float* v0 = hV + (n0)     * 128 + ks * 32 + hi * 8;
    const float* v1 = hV + (n0 + 1) * 128 + ks * 32 + hi * 8;
    bf16x8 a0 = cvt8(*(const float4*)v0, *(const float4*)(v0 + 4));
    bf16x8 a1 = cvt8(*(const float4*)v1, *(const float4*)(v1 + 4));
#pragma unroll
    for (int nn = 0; nn < 2; nn++) {
      bf16x8 b = *(const bf16x8*)(W1p + ((ks * 8 + w * 2 + nn) << 9) + lane * 8);
#pragma unroll
      for (int m = 0; m < 3; m++) {
        acc[0][m][nn] = MFMA(a0, b, acc[0][m][nn], 0, 0, 0);
        acc[1][m][nn] = MFMA(a1, b, acc[1][m][nn], 0, 0, 0);
      }
    }
  }
#pragma unroll
  for (int p = 0; p < 3; p++)
    *(bf16x8*)(lds + tdst[p]) = cvt8(pA1[p], pA2[p]);      // e0 -> buf0
#pragma unroll
  for (int p = 0; p < 3; p++) { pA1[p] = *(const float4*)(tsrc[p] + 128); pA2[p] = *(const float4*)(tsrc[p] + 132); }  // e2
  bar_lgkm();

  // ---- main loop: hE chunks e=0..5 (k-steps 4..15), 1 lgkm-barrier/chunk ----
#pragma unroll 1
  for (int i = 0; i < 6; ++i) {
    // 1) publish chunk e_{i+1} into buf[(i+1)&1] (regs loaded 2 iters ago)
    char* wbuf = lds + ((i + 1) & 1) * 12288;
    if (i < 5) {
      if (i & 1) {
#pragma unroll
        for (int p = 0; p < 3; p++) *(bf16x8*)(wbuf + tdst[p]) = cvt8(pA1[p], pA2[p]);
      } else {
#pragma unroll
        for (int p = 0; p < 3; p++) *(bf16x8*)(wbuf + tdst[p]) = cvt8(pB1[p], pB2[p]);
      }
    }
    // 2) weight-frag loads for chunk i — BEFORE the hE prefetch issue
    bf16x8 bb[2][2];
#pragma unroll
    for (int ks32 = 0; ks32 < 2; ++ks32)
#pragma unroll
      for (int nn = 0; nn < 2; nn++)
        bb[ks32][nn] = *(const bf16x8*)(W1p + (((4 + i * 2 + ks32) * 8 + w * 2 + nn) << 9) + lane * 8);
    // 3) issue hE loads for chunk e_{i+3} into the set just published
    if (i <= 2) {
      const int of = (i + 3) * 64;
      if (i & 1) {
#pragma unroll
        for (int p = 0; p < 3; p++) { pA1[p] = *(const float4*)(tsrc[p] + of); pA2[p] = *(const float4*)(tsrc[p] + of + 4); }
      } else {
#pragma unroll
        for (int p = 0; p < 3; p++) { pB1[p] = *(const float4*)(tsrc[p] + of); pB2[p] = *(const float4*)(tsrc[p] + of + 4); }
      }
    }
    // 4) compute chunk e_i from buf[i&1]
    {
      const char* Ab = lds + (i & 1) * 12288;
#pragma unroll
      for (int ks32 = 0; ks32 < 2; ++ks32) {
        bf16x8 a[2][3];
#pragma unroll
        for (int nl = 0; nl < 2; nl++)
#pragma unroll
          for (int m = 0; m < 3; m++) {
            int row = nl * 48 + m * 16 + lo;
            a[nl][m] = *(const bf16x8*)(Ab + row * 128 + ((ks32 * 64 + hi * 16) ^ ((row & 7) << 4)));
          }
#pragma unroll
        for (int nn = 0; nn < 2; nn++)
#pragma unroll
          for (int nl = 0; nl < 2; nl++)
#pragma unroll
            for (int m = 0; m < 3; m++)
              acc[nl][m][nn] = MFMA(a[nl][m], bb[ks32][nn], acc[nl][m][nn], 0, 0, 0);
      }
    }
    if (i < 5) bar_lgkm();
  }

  // ---- layers 2 and 3: A[96,128] @ W[128,128], X lives in the A region ----
#pragma unroll 1
  for (int layer = 0; layer < 2; ++layer) {
    const float*  bv = layer ? b2 : b1;
    const __bf16* Wp = wsb + (layer ? OFF_W3P : OFF_W2P);
    __syncthreads();   // everyone done reading lds (GEMM1 or previous layer)
#pragma unroll
    for (int nn = 0; nn < 2; nn++) {
      int col = (w * 2 + nn) * 16 + lo;
      float bc = bv[col];
#pragma unroll
      for (int nl = 0; nl < 2; nl++)
#pragma unroll
        for (int m = 0; m < 3; m++)
#pragma unroll
          for (int i = 0; i < 4; i++) {
            int row = nl * 48 + m * 16 + hi * 4 + i;
            float g = gelu_f(acc[nl][m][nn][i] + bc);
            *(__bf16*)(lds + row * 256 + ((col * 2) ^ ((row & 7) << 4))) = (__bf16)g;
            acc[nl][m][nn][i] = 0.f;
          }
    }
    __syncthreads();   // X visible to all waves
#pragma unroll 1
    for (int kc2 = 0; kc2 < 2; ++kc2) {
#pragma unroll
      for (int ks32 = 0; ks32 < 2; ++ks32) {
        int ks = kc2 * 2 + ks32;
        bf16x8 bb[2];
#pragma unroll
        for (int nn = 0; nn < 2; nn++)
          bb[nn] = *(const bf16x8*)(Wp + ((ks * 8 + w * 2 + nn) << 9) + lane * 8);
        bf16x8 a[2][3];
#pragma unroll
        for (int nl = 0; nl < 2; nl++)
#pragma unroll
          for (int m = 0; m < 3; m++) {
            int row = nl * 48 + m * 16 + lo;
            a[nl][m] = *(const bf16x8*)(lds + row * 256 + ((kc2 * 128 + ks32 * 64 + hi * 16) ^ ((row & 7) << 4)));
          }
#pragma unroll
        for (int nn = 0; nn < 2; nn++)
#pragma unroll
          for (int nl = 0; nl < 2; nl++)
#pragma unroll
            for (int m = 0; m < 3; m++)
              acc[nl][m][nn] = MFMA(a[nl][m], bb[nn], acc[nl][m][nn], 0, 0, 0);
      }
    }
  }

  // ---- epilogue: + b3, * mask_attend, sum over 48 rows per node, /SCALE ----
#pragma unroll
  for (int nl = 0; nl < 2; nl++) {
    float msk[12];
#pragma unroll
    for (int m = 0; m < 3; m++)
#pragma unroll
      for (int i = 0; i < 4; i++)
        msk[m * 4 + i] = mask_att[(n0 + nl) * 48 + m * 16 + hi * 4 + i];
#pragma unroll
    for (int nn = 0; nn < 2; nn++) {
      int col = (w * 2 + nn) * 16 + lo;
      float bc = b3[col];
      float s = 0.f;
#pragma unroll
      for (int m = 0; m < 3; m++)
#pragma unroll
        for (int i = 0; i < 4; i++)
          s += (acc[nl][m][nn][i] + bc) * msk[m * 4 + i];
      s += __shfl_xor(s, 16);
      s += __shfl_xor(s, 32);
      if (hi == 0)
        dh[(n0 + nl) * 128 + col] = s * (1.0f / 30.0f);
    }
  }
}

// ---------------- kernel 2: LN1 + FFN + LN2 + mask ----------------
// block = 16 nodes, 4 waves
__global__ __launch_bounds__(256, 2) void node_ffn_kernel(
    const float* __restrict__ hV, const float* __restrict__ maskV,
    const __bf16* __restrict__ wsb, const float* __restrict__ dh,
    const float* __restrict__ Winb, const float* __restrict__ Woutb,
    const float* __restrict__ ns1, const float* __restrict__ no1,
    const float* __restrict__ ns2, const float* __restrict__ no2,
    float* __restrict__ out)
{
  __shared__ char lds2[36864];
  char*  xA  = lds2;                    // [16][256B] bf16, swizzled
  float* hvn = (float*)(lds2 + 4096);   // [16][128] f32
  char*  A2  = lds2 + 12288;            // [16][1024B] bf16, swizzled
  float* red = (float*)(lds2 + 28672);  // [16][128] f32

  const __bf16* Winp  = wsb + OFF_WINP;
  const __bf16* Woutp = wsb + OFF_WOUTP;

  const int tid = threadIdx.x;
  const int w = tid >> 6, lane = tid & 63;
  const int lo = lane & 15, hi = lane >> 4;
  const int n0 = blockIdx.x * 16;

  const int row = tid >> 4;
  const int sg  = tid & 15;
  const int node = n0 + row;

  // Phase 0: x = h_V + dh, LN1 -> hvn (f32) and xA (bf16)
  {
    const float* pv = hV + node * 128 + sg * 8;
    const float* pd = dh + node * 128 + sg * 8;
    float4 a0 = *(const float4*)pv;
    float4 a1 = *(const float4*)(pv + 4);
    float4 d0 = *(const float4*)pd;
    float4 d1 = *(const float4*)(pd + 4);
    float x[8] = { a0.x + d0.x, a0.y + d0.y, a0.z + d0.z, a0.w + d0.w,
                   a1.x + d1.x, a1.y + d1.y, a1.z + d1.z, a1.w + d1.w };
    float s = 0.f, sq = 0.f;
#pragma unroll
    for (int j = 0; j < 8; j++) { s += x[j]; sq += x[j] * x[j]; }
#pragma unroll
    for (int off = 8; off >= 1; off >>= 1) { s += __shfl_xor(s, off); sq += __shfl_xor(sq, off); }
    float mean = s * (1.f / 128.f);
    float var  = sq * (1.f / 128.f) - mean * mean;
    float rs = rsqrtf(var + 1e-5f);
    bf16x8 vb;
    float yv[8];
#pragma unroll
    for (int j = 0; j < 8; j++) {
      int col = sg * 8 + j;
      float y = (x[j] - mean) * rs * ns1[col] + no1[col];
      yv[j] = y; vb[j] = (__bf16)y;
    }
    *(float4*)(hvn + row * 128 + sg * 8)     = make_float4(yv[0], yv[1], yv[2], yv[3]);
    *(float4*)(hvn + row * 128 + sg * 8 + 4) = make_float4(yv[4], yv[5], yv[6], yv[7]);
    *(bf16x8*)(xA + row * 256 + ((sg * 16) ^ ((row & 7) << 4))) = vb;
  }
  __syncthreads();

  // Phase 1: [16,128] @ Win -> [16,512]
  f32x4 acc[8];
#pragma unroll
  for (int n = 0; n < 8; n++) { acc[n][0] = 0.f; acc[n][1] = 0.f; acc[n][2] = 0.f; acc[n][3] = 0.f; }
#pragma unroll
  for (int ks = 0; ks < 4; ks++) {
    const int kb = (ks * 32 + hi * 8) * 2;
    bf16x8 a = *(const bf16x8*)(xA + lo * 256 + (kb ^ ((lo & 7) << 4)));
#pragma unroll
    for (int n = 0; n < 8; n++) {
      int ng = w * 8 + n;
      bf16x8 b = *(const bf16x8*)(Winp + ((ks * 32 + ng) << 9) + lane * 8);
      acc[n] = MFMA(a, b, acc[n], 0, 0, 0);
    }
  }
  // Phase 2: gelu -> A2
#pragma unroll
  for (int n = 0; n < 8; n++) {
    int col = w * 128 + n * 16 + lo;
    float bc = Winb[col];
#pragma unroll
    for (int i = 0; i < 4; i++) {
      int r2 = hi * 4 + i;
      float g = gelu_f(acc[n][i] + bc);
      *(__bf16*)(A2 + r2 * 1024 + ((col * 2) ^ ((r2 & 7) << 4))) = (__bf16)g;
    }
  }
  __syncthreads();

  // Phase 3: [16,512] @ Wout -> [16,128]
  f32x4 acc2[2];
  acc2[0][0] = 0.f; acc2[0][1] = 0.f; acc2[0][2] = 0.f; acc2[0][3] = 0.f;
  acc2[1][0] = 0.f; acc2[1][1] = 0.f; acc2[1][2] = 0.f; acc2[1][3] = 0.f;
#pragma unroll
  for (int ks = 0; ks < 16; ks++) {
    const int kb = (ks * 32 + hi * 8) * 2;
    bf16x8 a = *(const bf16x8*)(A2 + lo * 1024 + (kb ^ ((lo & 7) << 4)));
#pragma unroll
    for (int n = 0; n < 2; n++) {
      int ng = w * 2 + n;
      bf16x8 b = *(const bf16x8*)(Woutp + ((ks * 8 + ng) << 9) + lane * 8);
      acc2[n] = MFMA(a, b, acc2[n], 0, 0, 0);
    }
  }
  // Phase 4: + bias -> red
#pragma unroll
  for (int n = 0; n < 2; n++) {
    int col = w * 32 + n * 16 + lo;
    float bc = Woutb[col];
#pragma unroll
    for (int i = 0; i < 4; i++) {
      int r2 = hi * 4 + i;
      red[r2 * 128 + col] = acc2[n][i] + bc;
    }
  }
  __syncthreads();

  // Phase 5: LN2(hvn + red) * mask_V -> out
  {
    const float* ph = hvn + row * 128 + sg * 8;
    const float* pr = red + row * 128 + sg * 8;
    float4 h0 = *(const float4*)ph;
    float4 h1 = *(const float4*)(ph + 4);
    float4 r0 = *(const float4*)pr;
    float4 r1 = *(const float4*)(pr + 4);
    float x[8] = { h0.x + r0.x, h0.y + r0.y, h0.z + r0.z, h0.w + r0.w,
                   h1.x + r1.x, h1.y + r1.y, h1.z + r1.z, h1.w + r1.w };
    float s = 0.f, sq = 0.f;
#pragma unroll
    for (int j = 0; j < 8; j++) { s += x[j]; sq += x[j] * x[j]; }
#pragma unroll
    for (int off = 8; off >= 1; off >>= 1) { s += __shfl_xor(s, off); sq += __shfl_xor(sq, off); }
    float mean = s * (1.f / 128.f);
    float var  = sq * (1.f / 128.f) - mean * mean;
    float rs = rsqrtf(var + 1e-5f);
    float mv = maskV[node];
    float o[8];
#pragma unroll
    for (int j = 0; j < 8; j++) {
      int col = sg * 8 + j;
      o[j] = mv * ((x[j] - mean) * rs * ns2[col] + no2[col]);
    }
    *(float4*)(out + node * 128 + sg * 8)     = make_float4(o[0], o[1], o[2], o[3]);
    *(float4*)(out + node * 128 + sg * 8 + 4) = make_float4(o[4], o[5], o[6], o[7]);
  }
}

extern "C" void kernel_launch(void* const* d_in, const int* in_sizes, int n_in,
                              void* d_out, int out_size, void* d_ws, size_t ws_size,
                              hipStream_t stream)
{
  (void)in_sizes; (void)n_in; (void)out_size; (void)ws_size;
  const float* hV   = (const float*)d_in[0];
  const float* hE   = (const float*)d_in[1];
  const float* mV   = (const float*)d_in[2];
  const float* mAtt = (const float*)d_in[3];
  const float* W1   = (const float*)d_in[4];
  const float* b1   = (const float*)d_in[5];
  const float* W2   = (const float*)d_in[6];
  const float* b2   = (const float*)d_in[7];
  const float* W3   = (const float*)d_in[8];
  const float* b3   = (const float*)d_in[9];
  const float* Win  = (const float*)d_in[10];
  const float* binb = (const float*)d_in[11];
  const float* Wout = (const float*)d_in[12];
  const float* bout = (const float*)d_in[13];
  const float* ns1  = (const float*)d_in[14];
  const float* no1  = (const float*)d_in[15];
  const float* ns2  = (const float*)d_in[16];
  const float* no2  = (const float*)d_in[17];

  __bf16* wsb = (__bf16*)d_ws;
  float* dh   = (float*)((char*)d_ws + OFF_DH_BYTES);
  float* out  = (float*)d_out;

  prep_kernel<<<NPACK / 256, 256, 0, stream>>>(W1, W2, W3, Win, Wout, wsb);
  edge_mlp_kernel<<<2048, 256, 0, stream>>>(hE, hV, mAtt, wsb, b1, b2, b3, dh);
  node_ffn_kernel<<<256, 256, 0, stream>>>(hV, mV, wsb, dh, binb, bout,
                                           ns1, no1, ns2, no2, out);
}